// Round 4
// baseline (6916.160 us; speedup 1.0000x reference)
//
#include <hip/hip_runtime.h>
#include <cstddef>

#define HD 256      // hidden channels
#define CD 16       // data channels
#define BLOCK 256   // 4 waves; thread t owns hidden column t
#define W0REG 144   // W0 rows 0..143 in registers (per-thread column slice)
#define W0LDS 112   // W0 rows 144..255 in LDS, row-major [row][col]

// LDS: 112*256*4 + 3*1024 + 256 = 118,016 B < 163,840 B
struct alignas(16) SMem {
  float w0L[W0LDS * HD];   // rows 144..255 of W0, [row][col] (lane-consecutive reads)
  float hA[HD];            // input-layer output
  float hB[HD];            // prop-layer-0 output
  float hC[HD];            // prop-layer-1 output
  float op[4][CD];         // per-wave out-layer partials
};

__global__ __launch_bounds__(BLOCK, 1)
void decoder_persistent(const float* __restrict__ y0,
                        const float* __restrict__ in_w,
                        const float* __restrict__ in_b,
                        const float* __restrict__ out_w,
                        const float* __restrict__ out_b,
                        const float* __restrict__ prop_w,
                        const float* __restrict__ prop_b,
                        const float* __restrict__ cutoff,
                        const int*   __restrict__ plen,
                        float* __restrict__ out)
{
  __shared__ SMem sm;
  const int b  = blockIdx.x;
  const int t  = threadIdx.x;
  const int l  = t & 63;     // lane
  const int e  = t >> 6;     // wave
  const int oc = l & 15;     // out-layer column this lane helps with
  const int og = l >> 4;     // out-layer row-group within wave
  const int T  = plen[0];
  const float ct  = cutoff[0];
  const float dtc = 1e-6f;

  const float* W0g = prop_w + (size_t)b * 2u * HD * HD;
  const float* W1g = W0g + HD * HD;
  const float* Wig = in_w  + (size_t)b * CD * HD;
  const float* Wog = out_w + (size_t)b * HD * CD;

  // ---------------- one-time register weight caches (column slices) ----------
  float winr[CD];
#pragma unroll
  for (int c = 0; c < CD; ++c) winr[c] = Wig[c * HD + t];

  float w0r[W0REG];
#pragma unroll
  for (int r = 0; r < W0REG; ++r) w0r[r] = W0g[(size_t)r * HD + t];

  float w1r[HD];
#pragma unroll
  for (int r = 0; r < HD; ++r) w1r[r] = W1g[(size_t)r * HD + t];

  // out layer: lane covers rows e*64 + og*16 .. +15 of column oc (wave-redundant over e)
  float woutr[16];
#pragma unroll
  for (int j = 0; j < 16; ++j) woutr[j] = Wog[(size_t)(e * 64 + og * 16 + j) * CD + oc];

  const float binr  = in_b[(size_t)b * HD + t];
  const float b0r   = prop_b[((size_t)b * 2) * HD + t];
  const float b1r   = prop_b[((size_t)b * 2 + 1) * HD + t];
  const float boutr = out_b[(size_t)b * CD + oc];
  float ymine = y0[(size_t)b * CD + oc];   // wave-redundant: lane holds y[oc]

  // ---------------- one-time LDS fill: W0 rows 144..255, row-major ----------
  for (int i = t; i < W0LDS * (HD / 4); i += BLOCK) {
    const int L = i >> 6;      // lds row 0..111  (global row 144+L)
    const int q = i & 63;      // float4 col group
    *(float4*)(sm.w0L + L * HD + q * 4) =
        *(const float4*)(W0g + (size_t)(W0REG + L) * HD + q * 4);
  }
  __syncthreads();

  // two sub-base pointers keep ds offsets within the 16-bit immediate
  const float* w0La = sm.w0L + t;             // rows 0..63  (lds-local)
  const float* w0Lb = sm.w0L + 64 * HD + t;   // rows 64..111

  float* outb = out + (size_t)b * CD * T;

  for (int step = 0; step < T; ++step) {
    // ---- A: input layer (wave-local; y via shfl broadcast) ----
    {
      float acc = binr;
#pragma unroll
      for (int c = 0; c < CD; ++c) {
        const float yc = __shfl(ymine, (l & 48) + c);
        acc = fmaf(yc, winr[c], acc);
      }
      sm.hA[t] = fmaxf(acc, 0.0f);
    }
    __syncthreads();   // B1

    // ---- B: prop layer 0: col t = relu(b0 + sum_r hA[r]*W0[r][t]) ----
    {
      float a0 = b0r, a1 = 0.f, a2 = 0.f, a3 = 0.f;
#pragma unroll
      for (int rq = 0; rq < W0REG / 4; ++rq) {         // rows 0..143 (registers)
        const float4 hv = *(const float4*)(sm.hA + rq * 4);
        a0 = fmaf(hv.x, w0r[rq * 4 + 0], a0);
        a1 = fmaf(hv.y, w0r[rq * 4 + 1], a1);
        a2 = fmaf(hv.z, w0r[rq * 4 + 2], a2);
        a3 = fmaf(hv.w, w0r[rq * 4 + 3], a3);
      }
#pragma unroll
      for (int rq = 0; rq < 16; ++rq) {                // rows 144..207 (LDS, base a)
        const float4 hv = *(const float4*)(sm.hA + W0REG + rq * 4);
        a0 = fmaf(hv.x, w0La[(rq * 4 + 0) * HD], a0);
        a1 = fmaf(hv.y, w0La[(rq * 4 + 1) * HD], a1);
        a2 = fmaf(hv.z, w0La[(rq * 4 + 2) * HD], a2);
        a3 = fmaf(hv.w, w0La[(rq * 4 + 3) * HD], a3);
      }
#pragma unroll
      for (int rq = 0; rq < 12; ++rq) {                // rows 208..255 (LDS, base b)
        const float4 hv = *(const float4*)(sm.hA + W0REG + 64 + rq * 4);
        a0 = fmaf(hv.x, w0Lb[(rq * 4 + 0) * HD], a0);
        a1 = fmaf(hv.y, w0Lb[(rq * 4 + 1) * HD], a1);
        a2 = fmaf(hv.z, w0Lb[(rq * 4 + 2) * HD], a2);
        a3 = fmaf(hv.w, w0Lb[(rq * 4 + 3) * HD], a3);
      }
      sm.hB[t] = fmaxf((a0 + a1) + (a2 + a3), 0.0f);
    }
    __syncthreads();   // B2

    // ---- C: prop layer 1: col t, all-register weights ----
    {
      float c0 = b1r, c1 = 0.f, c2 = 0.f, c3 = 0.f;
#pragma unroll
      for (int rq = 0; rq < HD / 4; ++rq) {
        const float4 hv = *(const float4*)(sm.hB + rq * 4);
        c0 = fmaf(hv.x, w1r[rq * 4 + 0], c0);
        c1 = fmaf(hv.y, w1r[rq * 4 + 1], c1);
        c2 = fmaf(hv.z, w1r[rq * 4 + 2], c2);
        c3 = fmaf(hv.w, w1r[rq * 4 + 3], c3);
      }
      sm.hC[t] = fmaxf((c0 + c1) + (c2 + c3), 0.0f);
    }
    __syncthreads();   // B3

    // ---- D: out-layer partials: wave e covers rows e*64..e*64+63 ----
    {
      float p = 0.f;
#pragma unroll
      for (int jq = 0; jq < 4; ++jq) {
        const float4 hv = *(const float4*)(sm.hC + e * 64 + og * 16 + jq * 4);
        p = fmaf(hv.x, woutr[jq * 4 + 0], p);
        p = fmaf(hv.y, woutr[jq * 4 + 1], p);
        p = fmaf(hv.z, woutr[jq * 4 + 2], p);
        p = fmaf(hv.w, woutr[jq * 4 + 3], p);
      }
      p += __shfl_xor(p, 16);
      p += __shfl_xor(p, 32);
      if (l < CD) sm.op[e][l] = p;
    }
    __syncthreads();   // B4

    // ---- E: finish (all threads redundantly): y update + store ----
    {
      const float s  = boutr + ((sm.op[0][oc] + sm.op[1][oc]) +
                                (sm.op[2][oc] + sm.op[3][oc]));
      const float yv = ymine + ct * tanhf(dtc * s / ct);
      ymine = yv;
      if (t < CD) outb[(size_t)t * T + step] = yv;   // wave 0, lanes 0..15
    }
    // no barrier needed: next A is wave-local; hA WAR covered by B2..B4,
    // op WAR covered by B1..B3 of the next step.
  }
}

extern "C" void kernel_launch(void* const* d_in, const int* in_sizes, int n_in,
                              void* d_out, int out_size, void* d_ws, size_t ws_size,
                              hipStream_t stream) {
  (void)in_sizes; (void)n_in; (void)out_size; (void)d_ws; (void)ws_size;
  const float* y0     = (const float*)d_in[0];
  const float* in_w   = (const float*)d_in[1];
  const float* in_b   = (const float*)d_in[2];
  const float* out_w  = (const float*)d_in[3];
  const float* out_b  = (const float*)d_in[4];
  const float* prop_w = (const float*)d_in[5];
  const float* prop_b = (const float*)d_in[6];
  const float* cutoff = (const float*)d_in[7];
  const int*   plen   = (const int*)d_in[8];
  float* out = (float*)d_out;

  decoder_persistent<<<256, BLOCK, 0, stream>>>(
      y0, in_w, in_b, out_w, out_b, prop_w, prop_b, cutoff, plen, out);
}

// Round 5
// 3459.666 us; speedup vs baseline: 1.9991x; 1.9991x over previous
//
#include <hip/hip_runtime.h>
#include <cstddef>

#define HD 256      // hidden channels
#define CD 16       // data channels
#define BLOCK 256   // 4 waves; wave e owns rows e*64..e*64+63; lane l owns cols 4l..4l+3
#define W0RROWS 32  // W0 rows per wave kept in registers (rows e*64+0..31)
#define W0LROWS 32  // W0 rows per wave kept in LDS      (rows e*64+32..63)

// LDS: 4*32*256*4 + 4*256*4 + 4*16*4 = 131072 + 4096 + 256 = 135,424 B < 163,840 B
struct alignas(16) SMem {
  float w0L[4 * W0LROWS * HD];  // [wave][row][col], b128-read cols 4l..4l+3
  float part[4][HD];            // per-wave partial sums (one live layer at a time)
  float op[4][CD];              // out-layer per-wave partials
};

__device__ __forceinline__ float rlane(float v, int lane) {
  return __uint_as_float(__builtin_amdgcn_readlane(__float_as_uint(v), lane));
}

__global__ __launch_bounds__(BLOCK, 1)
void decoder_persistent(const float* __restrict__ y0,
                        const float* __restrict__ in_w,
                        const float* __restrict__ in_b,
                        const float* __restrict__ out_w,
                        const float* __restrict__ out_b,
                        const float* __restrict__ prop_w,
                        const float* __restrict__ prop_b,
                        const float* __restrict__ cutoff,
                        const int*   __restrict__ plen,
                        float* __restrict__ out)
{
  __shared__ SMem sm;
  const int b  = blockIdx.x;
  const int t  = threadIdx.x;
  const int l  = t & 63;     // lane: owns cols 4l..4l+3 of its wave's row-slice
  const int e  = t >> 6;     // wave: owns rows e*64..e*64+63
  const int oc = l & 15;     // out-layer channel this lane reduces
  const int og = l >> 4;     // out-layer row-group within wave
  const int T  = plen[0];
  const float ct  = cutoff[0];
  const float sc  = 1e-6f / ct;   // dt / cutoff

  const float* W0g = prop_w + (size_t)b * 2u * HD * HD;
  const float* W1g = W0g + HD * HD;
  const float* Wig = in_w  + (size_t)b * CD * HD;
  const float* Wog = out_w + (size_t)b * HD * CD;

  // ---------------- one-time register weight caches ----------------
  // W0 rows e*64+0..31, cols 4l..4l+3 (coalesced float4 per wave)
  float4 w0r[W0RROWS];
#pragma unroll
  for (int j = 0; j < W0RROWS; ++j)
    w0r[j] = *(const float4*)(W0g + (size_t)(e * 64 + j) * HD + 4 * l);
  // W1 rows e*64+0..63, cols 4l..4l+3 (fully in registers)
  float4 w1r[64];
#pragma unroll
  for (int j = 0; j < 64; ++j)
    w1r[j] = *(const float4*)(W1g + (size_t)(e * 64 + j) * HD + 4 * l);
  // input layer: column t slice
  float winr[CD];
#pragma unroll
  for (int c = 0; c < CD; ++c) winr[c] = Wig[c * HD + t];
  // out layer: rows e*64+og*16.. of channel oc
  float woutr[16];
#pragma unroll
  for (int j = 0; j < 16; ++j) woutr[j] = Wog[(size_t)(e * 64 + og * 16 + j) * CD + oc];

  const float binr  = in_b[(size_t)b * HD + t];
  const float b0r   = prop_b[((size_t)b * 2) * HD + t];
  const float b1r   = prop_b[((size_t)b * 2 + 1) * HD + t];
  const float boutr = out_b[(size_t)b * CD + oc];
  float ylane = y0[(size_t)b * CD + oc];   // lane holds y[l&15] (wave-redundant)

  // ---------------- one-time LDS fill: W0 rows e2*64+32..63 per wave ----------
  for (int i = t; i < 4 * W0LROWS * (HD / 4); i += BLOCK) {
    const int g  = i >> 6;       // lds row 0..127
    const int q  = i & 63;       // float4 col group
    const int e2 = g >> 5;
    const int j2 = g & 31;
    *(float4*)(sm.w0L + g * HD + q * 4) =
        *(const float4*)(W0g + (size_t)(e2 * 64 + 32 + j2) * HD + q * 4);
  }
  __syncthreads();

  const float* w0Lb = sm.w0L + e * W0LROWS * HD;   // this wave's LDS weight slice
  float* outb = out + (size_t)b * CD * T;

  for (int step = 0; step < T; ++step) {
    // ---- IN: h1[t] = relu(bin + sum_c y[c]*Win[c][t]) — pure VALU ----
    float a = binr;
#pragma unroll
    for (int c = 0; c < CD; ++c) a = fmaf(rlane(ylane, c), winr[c], a);
    const float h1 = fmaxf(a, 0.0f);

    // ---- P0: prop-layer-0 partials over this wave's 64 rows ----
    float p0 = 0.f, p1 = 0.f, p2 = 0.f, p3 = 0.f;
#pragma unroll
    for (int j = 0; j < W0RROWS; ++j) {        // rows e*64+0..31 (registers)
      const float s = rlane(h1, j);
      p0 = fmaf(s, w0r[j].x, p0);
      p1 = fmaf(s, w0r[j].y, p1);
      p2 = fmaf(s, w0r[j].z, p2);
      p3 = fmaf(s, w0r[j].w, p3);
    }
#pragma unroll
    for (int j2 = 0; j2 < W0LROWS; ++j2) {     // rows e*64+32..63 (LDS b128)
      const float s = rlane(h1, 32 + j2);
      const float4 w = *(const float4*)(w0Lb + j2 * HD + 4 * l);
      p0 = fmaf(s, w.x, p0);
      p1 = fmaf(s, w.y, p1);
      p2 = fmaf(s, w.z, p2);
      p3 = fmaf(s, w.w, p3);
    }
    { float4 v; v.x = p0; v.y = p1; v.z = p2; v.w = p3;
      *(float4*)(&sm.part[e][4 * l]) = v; }
    __syncthreads();   // A: partials visible

    // ---- combine -> h2 (thread t owns column t; value stays in lane) ----
    const float h2 = fmaxf(b0r + ((sm.part[0][t] + sm.part[1][t]) +
                                  (sm.part[2][t] + sm.part[3][t])), 0.0f);
    __syncthreads();   // B: part free for re-write

    // ---- P1: prop-layer-1 partials, all-register weights ----
    p0 = 0.f; p1 = 0.f; p2 = 0.f; p3 = 0.f;
#pragma unroll
    for (int j = 0; j < 64; ++j) {
      const float s = rlane(h2, j);
      p0 = fmaf(s, w1r[j].x, p0);
      p1 = fmaf(s, w1r[j].y, p1);
      p2 = fmaf(s, w1r[j].z, p2);
      p3 = fmaf(s, w1r[j].w, p3);
    }
    { float4 v; v.x = p0; v.y = p1; v.z = p2; v.w = p3;
      *(float4*)(&sm.part[e][4 * l]) = v; }
    __syncthreads();   // C: partials visible

    // ---- combine -> h3 ----
    const float h3 = fmaxf(b1r + ((sm.part[0][t] + sm.part[1][t]) +
                                  (sm.part[2][t] + sm.part[3][t])), 0.0f);

    // ---- OUT: lane reduces rows og*16..+15 of channel oc ----
    float p = 0.f;
#pragma unroll
    for (int j = 0; j < 16; ++j)
      p = fmaf(__shfl(h3, og * 16 + j), woutr[j], p);
    p += __shfl_xor(p, 16);
    p += __shfl_xor(p, 32);
    if (l < CD) sm.op[e][l] = p;
    __syncthreads();   // E: op visible (also protects part WAR for next step)

    // ---- finish: all threads redundantly update their y channel ----
    const float s  = boutr + ((sm.op[0][oc] + sm.op[1][oc]) +
                              (sm.op[2][oc] + sm.op[3][oc]));
    const float yv = ylane + ct * tanhf(s * sc);
    ylane = yv;
    if (t < CD) outb[(size_t)t * T + step] = yv;   // wave 0, lanes 0..15
    // no trailing barrier: next IN/P0 are LDS-free until the pre-A write,
    // and op re-write happens after next step's A/B/C barriers.
  }
}

extern "C" void kernel_launch(void* const* d_in, const int* in_sizes, int n_in,
                              void* d_out, int out_size, void* d_ws, size_t ws_size,
                              hipStream_t stream) {
  (void)in_sizes; (void)n_in; (void)out_size; (void)d_ws; (void)ws_size;
  const float* y0     = (const float*)d_in[0];
  const float* in_w   = (const float*)d_in[1];
  const float* in_b   = (const float*)d_in[2];
  const float* out_w  = (const float*)d_in[3];
  const float* out_b  = (const float*)d_in[4];
  const float* prop_w = (const float*)d_in[5];
  const float* prop_b = (const float*)d_in[6];
  const float* cutoff = (const float*)d_in[7];
  const int*   plen   = (const int*)d_in[8];
  float* out = (float*)d_out;

  decoder_persistent<<<256, BLOCK, 0, stream>>>(
      y0, in_w, in_b, out_w, out_b, prop_w, prop_b, cutoff, plen, out);
}